// Round 12
// baseline (518.340 us; speedup 1.0000x reference)
//
#include <hip/hip_runtime.h>
#include <hip/hip_bf16.h>

#define KK 5
constexpr int N0 = 78400;     // B*28*28
constexpr int E0 = 627200;    // N0*8
constexpr int N1 = 19600;     // B*14*14
constexpr int E1 = 156800;    // N1*8
constexpr int C1 = 32, C2 = 64;
constexpr int BSZ = 100;
constexpr int FC1_IN = 3136, FC1_OUT = 512;
constexpr int NB1 = 1225;     // conv1 blocks (64 nodes each)
constexpr int NB2 = 1225;     // conv2 blocks (16 nodes each)
constexpr int KEXT = 832;     // 800 tap-space + 32 root channels
constexpr int ULS = 836;      // LDS fp32 U row stride

typedef __attribute__((ext_vector_type(8))) short bf16x8;
typedef __attribute__((ext_vector_type(4))) float f32x4;

__device__ __forceinline__ unsigned short f2bf(float f) {
    union { float f; unsigned u; } v; v.f = f;
    unsigned u = v.u;
    unsigned r = (u + 0x7FFF + ((u >> 16) & 1)) >> 16;   // RNE
    return (unsigned short)r;
}

__device__ __forceinline__ void taps4(float px, float py,
                                      int& a00, int& a01, int& a10, int& a11,
                                      float& fx, float& fy) {
    float kfx = floorf(px), kfy = floorf(py);
    fx = px - kfx; fy = py - kfy;
    int k0x = min(max((int)kfx, 0), KK - 1);
    int k0y = min(max((int)kfy, 0), KK - 1);
    int k1x = min(k0x + 1, KK - 1), k1y = min(k0y + 1, KK - 1);
    a00 = k0x * KK + k0y; a01 = k0x * KK + k1y;
    a10 = k1x * KK + k0y; a11 = k1x * KK + k1y;
}

// ---- pass 1: histogram edges into conv-block-aligned buckets ----
__global__ void count_buckets(const int* __restrict__ ei0, const int* __restrict__ ei1,
                              int* __restrict__ bins) {
    int gid = blockIdx.x * blockDim.x + threadIdx.x;
    if (gid < E0) {
        atomicAdd(&bins[ei0[E0 + gid] >> 6], 1);
    } else if (gid < E0 + E1) {
        atomicAdd(&bins[1280 + (ei1[E1 + (gid - E0)] >> 4)], 1);
    }
}

// ---- pass 2: exclusive prefix over both halves; emit offsets + cursors ----
__global__ void prefix_scan(const int* __restrict__ bins, int* __restrict__ off1,
                            int* __restrict__ off2, int* __restrict__ cursor) {
    __shared__ int tmp[2560];
    __shared__ int part[256];
    int t = threadIdx.x;
    for (int i = t; i < 2560; i += 256) tmp[i] = bins[i];
    __syncthreads();
    int base = t * 10;
    int s = 0;
#pragma unroll
    for (int k = 0; k < 10; k++) { int c = tmp[base + k]; tmp[base + k] = s; s += c; }
    part[t] = s;
    __syncthreads();
    if (t == 0) { int s2 = 0; for (int k = 0; k < 128; k++) { int c = part[k]; part[k] = s2; s2 += c; } }
    if (t == 1) { int s2 = 0; for (int k = 128; k < 256; k++) { int c = part[k]; part[k] = s2; s2 += c; } }
    __syncthreads();
    int add = part[t];
#pragma unroll
    for (int k = 0; k < 10; k++) tmp[base + k] += add;
    __syncthreads();
    for (int i = t; i < NB1; i += 256) { off1[i] = tmp[i]; cursor[i] = tmp[i]; }
    for (int i = t; i < NB2; i += 256) { off2[i] = tmp[1280 + i]; cursor[1280 + i] = tmp[1280 + i]; }
    if (t == 0) { off1[NB1] = E0; off2[NB2] = E1; }
}

// ---- pass 3: materialize 16B payload per edge, bucket-contiguous ----
__global__ void scatter_pay(const float* __restrict__ x,
                            const float* __restrict__ ps0, const int* __restrict__ ei0,
                            const float* __restrict__ ps1, const int* __restrict__ ei1,
                            int* __restrict__ cursor,
                            int4* __restrict__ pay1, int4* __restrict__ pay2) {
    int gid = blockIdx.x * blockDim.x + threadIdx.x;
    if (gid < E0) {
        int e = gid;
        int src = ei0[e], dst = ei0[E0 + e];
        int a00, a01, a10, a11; float fx, fy;
        taps4(ps0[2 * e] * (KK - 1), ps0[2 * e + 1] * (KK - 1), a00, a01, a10, a11, fx, fy);
        int meta = (dst & 63) | (a00 << 6) | (a01 << 11) | (a10 << 16) | (a11 << 21);
        int pos = atomicAdd(&cursor[dst >> 6], 1);
        int4 pl;
        pl.x = __float_as_int(x[src]); pl.y = meta;
        pl.z = __float_as_int(fx); pl.w = __float_as_int(fy);
        pay1[pos] = pl;
    } else if (gid < E0 + E1) {
        int e = gid - E0;
        int src = ei1[e], dst = ei1[E1 + e];
        int a00, a01, a10, a11; float fx, fy;
        taps4(ps1[2 * e] * (KK - 1), ps1[2 * e + 1] * (KK - 1), a00, a01, a10, a11, fx, fy);
        int meta = (dst & 15) | (a00 << 4) | (a01 << 9) | (a10 << 14) | (a11 << 19);
        int pos = atomicAdd(&cursor[1280 + (dst >> 4)], 1);
        int4 pl;
        pl.x = src; pl.y = meta;
        pl.z = __float_as_int(fx); pl.w = __float_as_int(fy);
        pay2[pos] = pl;
    }
}

// ---- conv1 fused: block = 64 nodes + its contiguous payload segment.
//      LDS-atomic tap-space accumulate, then h1 = ELU((S@W1)/deg + x*root + b).
__global__ void conv1_fused(const int4* __restrict__ pay1, const int* __restrict__ off1,
                            const float* __restrict__ x, const float* __restrict__ W1,
                            const float* __restrict__ root, const float* __restrict__ bias,
                            float* __restrict__ h1) {
    __shared__ float S[64 * 25];      // 6.4 KB
    __shared__ int degs[64];
    int t = threadIdx.x;
    int nb = blockIdx.x * 64;
    for (int i = t; i < 64 * 25; i += 256) S[i] = 0.f;
    if (t < 64) degs[t] = 0;
    __syncthreads();
    int e0 = off1[blockIdx.x], e1 = off1[blockIdx.x + 1];
    for (int e = e0 + t; e < e1; e += 256) {
        int4 p = pay1[e];
        float xv = __int_as_float(p.x);
        int meta = p.y;
        float fx = __int_as_float(p.z), fy = __int_as_float(p.w);
        int ldst = meta & 63;
        int a00 = (meta >> 6) & 31, a01 = (meta >> 11) & 31;
        int a10 = (meta >> 16) & 31, a11 = (meta >> 21) & 31;
        float gx = 1.f - fx, gy = 1.f - fy;
        float* sp = S + ldst * 25;
        atomicAdd(&sp[a00], gx * gy * xv);
        atomicAdd(&sp[a01], gx * fy * xv);
        atomicAdd(&sp[a10], fx * gy * xv);
        atomicAdd(&sp[a11], fx * fy * xv);
        atomicAdd(&degs[ldst], 1);
    }
    __syncthreads();
    int o = t & 31, ng = t >> 5;
    float w1c[25];
#pragma unroll
    for (int a = 0; a < 25; a++) w1c[a] = W1[a * C1 + o];
    float ro = root[o], bo = bias[o];
    for (int j = 0; j < 8; j++) {
        int nl = ng * 8 + j;
        int n = nb + nl;
        float acc = 0.f;
#pragma unroll
        for (int a = 0; a < 25; a++) acc += S[nl * 25 + a] * w1c[a];
        float v = acc / fmaxf((float)degs[nl], 1.f) + x[n] * ro + bo;
        h1[n * C1 + o] = v > 0.f ? v : expm1f(v);
    }
}

// ---- pool1: [100,28,28,32] -> [100,14,14,32] ----
__global__ void pool1(const float* __restrict__ h1, float* __restrict__ p1) {
    int idx = blockIdx.x * blockDim.x + threadIdx.x;
    if (idx >= N1 * C1) return;
    int o = idx & 31; int t = idx >> 5;
    int c = t % 14; int r = (t / 14) % 14; int b = t / 196;
    const float* base = h1 + (((b * 28 + 2 * r) * 28 + 2 * c) * C1 + o);
    float m = fmaxf(fmaxf(base[0], base[C1]),
                    fmaxf(base[28 * C1], base[28 * C1 + C1]));
    p1[idx] = m;
}

// ---- w2t prep: bf16 transposed W2ext [64 o][832 k]; k<800 -> W2, else root2 ----
__global__ void w2t_prep(const float* __restrict__ W2, const float* __restrict__ root2,
                         unsigned short* __restrict__ w2t) {
    int idx = blockIdx.x * blockDim.x + threadIdx.x;
    if (idx >= 64 * KEXT) return;
    int o = idx / KEXT, k = idx - o * KEXT;
    float v = (k < 800) ? W2[k * 64 + o] : root2[(k - 800) * 64 + o];
    w2t[idx] = f2bf(v);
}

// ---- wt1 prep: fc1w [3136,512] fp32 -> transposed bf16 wt1[512][3136] ----
__global__ void wt1_prep(const float* __restrict__ w, unsigned short* __restrict__ wt1) {
    __shared__ unsigned short tile[64 * 66];
    int t = threadIdx.x;
    int k0 = blockIdx.x * 64, j0 = blockIdx.y * 64;
    int jj = t & 63, ks = t >> 6;
    for (int kk = ks; kk < 64; kk += 4)
        tile[kk * 66 + jj] = f2bf(w[(k0 + kk) * FC1_OUT + j0 + jj]);
    __syncthreads();
    int kk = t & 63, js = t >> 6;
    for (int j2 = js; j2 < 64; j2 += 4)
        wt1[(j0 + j2) * FC1_IN + k0 + kk] = tile[kk * 66 + j2];
}

// ---- conv2 fused (MFMA): block = 16 nodes + contiguous payload segment.
//  Phase1: LDS-atomic accumulate into U[16][832] (unscaled), deg counted.
//  Phase2: bf16 A-pack applies 1/deg (kc<25); h2 = ELU(U@w2t^T + b2) via MFMA.
__global__ __launch_bounds__(256, 3)
void conv2_fused(const float* __restrict__ p1, const int4* __restrict__ pay2,
                 const int* __restrict__ off2,
                 const unsigned short* __restrict__ w2t,
                 const float* __restrict__ b2, float* __restrict__ h2) {
    __shared__ float Ul[16 * ULS];          // 53.5 KB
    __shared__ int degs[16];
    int t = threadIdx.x;
    int nb = blockIdx.x * 16;
    int i = t & 31, g = t >> 5;             // channel lane, group 0..7
    for (int nn = g; nn < 16; nn += 8) {
        float* up = Ul + nn * ULS;
#pragma unroll
        for (int a = 0; a < 25; a++) up[a * 32 + i] = 0.f;
        up[800 + i] = p1[(nb + nn) * C1 + i];
    }
    if (t < 16) degs[t] = 0;
    __syncthreads();
    int e0 = off2[blockIdx.x], e1 = off2[blockIdx.x + 1];
    for (int e = e0 + g; e < e1; e += 8) {
        int4 p = pay2[e];                   // lane-uniform -> broadcast
        int src = p.x, meta = p.y;
        float fx = __int_as_float(p.z), fy = __int_as_float(p.w);
        int ldst = meta & 15;
        int a00 = (meta >> 4) & 31, a01 = (meta >> 9) & 31;
        int a10 = (meta >> 14) & 31, a11 = (meta >> 19) & 31;
        float xv = p1[src * C1 + i];        // coalesced 128B per group
        float gx = 1.f - fx, gy = 1.f - fy;
        float* up = Ul + ldst * ULS;
        atomicAdd(&up[a00 * 32 + i], gx * gy * xv);
        atomicAdd(&up[a01 * 32 + i], gx * fy * xv);
        atomicAdd(&up[a10 * 32 + i], fx * gy * xv);
        atomicAdd(&up[a11 * 32 + i], fx * fy * xv);
        if (i == 0) atomicAdd(&degs[ldst], 1);
    }
    __syncthreads();
    // phase 2: MFMA. wave wv -> o-tile. D[node=quad*4+r][o=lane&15]
    int wv = t >> 6, lane = t & 63, quad = lane >> 4, lrow = lane & 15;
    f32x4 acc = {0.f, 0.f, 0.f, 0.f};
    float invd = 1.f / fmaxf((float)degs[lrow], 1.f);
    const unsigned short* bbase = w2t + (wv * 16 + lrow) * KEXT;
    const float* abase = Ul + lrow * ULS;
#pragma unroll
    for (int kc = 0; kc < 26; kc++) {
        float4 a0 = *(const float4*)(abase + kc * 32 + quad * 8);
        float4 a1 = *(const float4*)(abase + kc * 32 + quad * 8 + 4);
        float s = (kc < 25) ? invd : 1.f;
        bf16x8 a;
        a[0] = (short)f2bf(a0.x * s); a[1] = (short)f2bf(a0.y * s);
        a[2] = (short)f2bf(a0.z * s); a[3] = (short)f2bf(a0.w * s);
        a[4] = (short)f2bf(a1.x * s); a[5] = (short)f2bf(a1.y * s);
        a[6] = (short)f2bf(a1.z * s); a[7] = (short)f2bf(a1.w * s);
        bf16x8 b = *(const bf16x8*)(bbase + kc * 32 + quad * 8);
        acc = __builtin_amdgcn_mfma_f32_16x16x32_bf16(a, b, acc, 0, 0, 0);
    }
    int o = wv * 16 + lrow;
    float bo = b2[o];
#pragma unroll
    for (int r = 0; r < 4; r++) {
        int node = quad * 4 + r;
        float v = acc[r] + bo;
        v = v > 0.f ? v : expm1f(v);
        h2[(nb + node) * C2 + o] = v;
    }
}

// ---- pool2 -> bf16 [112 x 3136], rows 100..111 zeroed (M-pad for MFMA) ----
__global__ void pool2b(const float* __restrict__ h2, unsigned short* __restrict__ p2b) {
    int idx = blockIdx.x * blockDim.x + threadIdx.x;
    if (idx >= 112 * FC1_IN) return;
    if (idx >= 100 * FC1_IN) { p2b[idx] = 0; return; }
    int o = idx & 63; int t2 = idx >> 6;
    int c = t2 % 14; int r = (t2 / 14) % 14; int b = t2 / 196;
    const float* base = h2 + (((b * 28 + 2 * r) * 28 + 2 * c) * C2 + o);
    float m = fmaxf(fmaxf(base[0], base[C2]),
                    fmaxf(base[28 * C2], base[28 * C2 + C2]));
    p2b[idx] = f2bf(m);
}

// ---- fc1 MFMA: [112,3136]bf16 @ wt1^T -> z1p fp32 partials (2 kz). ----
__global__ void gemm_fc1(const unsigned short* __restrict__ p2b,
                         const unsigned short* __restrict__ wt1,
                         float* __restrict__ z1p) {
    constexpr int AS = 232;              // 224 + 8 pad, 16B aligned
    __shared__ unsigned short as_[16 * AS];   // 7.4 KB
    int t = threadIdx.x;
    int jt = blockIdx.x, mt = blockIdx.y, kz = blockIdx.z;
    int wv = t >> 6, lane = t & 63, quad = lane >> 4, lrow = lane & 15;
    int m0 = mt * 16;
    int kbase = kz * 1568;
    const unsigned short* bbase = wt1 + (jt * 64 + wv * 16 + lrow) * FC1_IN + kbase;
    f32x4 acc = {0.f, 0.f, 0.f, 0.f};
    for (int ch = 0; ch < 7; ch++) {
        __syncthreads();
        for (int slot = t; slot < 448; slot += 256) {   // 16 rows x 28 uint4
            int r = slot / 28, c = slot - (slot / 28) * 28;
            *(uint4*)(as_ + r * AS + c * 8) =
                *(const uint4*)(p2b + (m0 + r) * FC1_IN + kbase + ch * 224 + c * 8);
        }
        __syncthreads();
        const unsigned short* ab = as_ + lrow * AS;
        const unsigned short* bb = bbase + ch * 224;
#pragma unroll
        for (int kk = 0; kk < 7; kk++) {
            bf16x8 a = *(const bf16x8*)(ab + kk * 32 + quad * 8);
            bf16x8 b = *(const bf16x8*)(bb + kk * 32 + quad * 8);
            acc = __builtin_amdgcn_mfma_f32_16x16x32_bf16(a, b, acc, 0, 0, 0);
        }
    }
    int n = jt * 64 + wv * 16 + lrow;
#pragma unroll
    for (int r = 0; r < 4; r++) {
        int m = m0 + quad * 4 + r;
        z1p[kz * (112 * FC1_OUT) + m * FC1_OUT + n] = acc[r];
    }
}

// ---- fc2 + log_softmax fused; sums 2 fc1 partials, applies fc1 bias+ELU ----
__global__ void fc2_lsm(const float* __restrict__ z1p, const float* __restrict__ fc1b,
                        const float* __restrict__ w, const float* __restrict__ fc2b,
                        float* __restrict__ out) {
    int b = blockIdx.x;
    int t = threadIdx.x;
    int wv = t >> 6;
    int lane = t & 63;
    float acc = 0.f;
#pragma unroll
    for (int m = 0; m < 8; m++) {
        int k = lane * 8 + m;
        float xv = fc1b[k] + z1p[b * FC1_OUT + k] + z1p[112 * FC1_OUT + b * FC1_OUT + k];
        xv = xv > 0.f ? xv : expm1f(xv);
        acc += xv * w[k * 10 + wv];
    }
#pragma unroll
    for (int off = 32; off > 0; off >>= 1) acc += __shfl_down(acc, off);
    __shared__ float zs[10];
    if (lane == 0) {
        float z = acc + fc2b[wv];
        zs[wv] = z > 0.f ? z : expm1f(z);
    }
    __syncthreads();
    if (t < 10) {
        float m = -1e30f;
        for (int jj = 0; jj < 10; jj++) m = fmaxf(m, zs[jj]);
        float s = 0.f;
        for (int jj = 0; jj < 10; jj++) s += expf(zs[jj] - m);
        out[b * 10 + t] = zs[t] - m - logf(s);
    }
}

extern "C" void kernel_launch(void* const* d_in, const int* in_sizes, int n_in,
                              void* d_out, int out_size, void* d_ws, size_t ws_size,
                              hipStream_t stream) {
    const float* x     = (const float*)d_in[0];
    const float* ps0   = (const float*)d_in[1];
    const float* ps1   = (const float*)d_in[2];
    const float* W1    = (const float*)d_in[3];
    const float* root1 = (const float*)d_in[4];
    const float* b1    = (const float*)d_in[5];
    const float* W2    = (const float*)d_in[6];
    const float* root2 = (const float*)d_in[7];
    const float* b2v   = (const float*)d_in[8];
    const float* fc1w  = (const float*)d_in[9];
    const float* fc1b  = (const float*)d_in[10];
    const float* fc2w  = (const float*)d_in[11];
    const float* fc2b  = (const float*)d_in[12];
    const int*   ei0   = (const int*)d_in[13];
    const int*   ei1   = (const int*)d_in[14];

    float* ws = (float*)d_ws;
    int*  bins   = (int*)ws;                       //      2,560  (memset boundary)
    int*  off1   = (int*)(ws + 2560);              //      1,232
    int*  off2   = (int*)(ws + 3792);              //      1,232
    int*  cursor = (int*)(ws + 5024);              //      2,560
    int4* pay1   = (int4*)(ws + 7584);             //  2,508,800 w (E0 x 16B)
    int4* pay2   = (int4*)(ws + 2516384);          //    627,200 w
    float* h1    = ws + 3143584;                   //  2,508,800
    float* p1    = ws + 5652384;                   //    627,200
    float* h2    = ws + 6279584;                   //  1,254,400
    unsigned short* p2b = (unsigned short*)(ws + 7533984);  // 175,616 w
    float* z1p   = ws + 7709600;                   //    114,688
    unsigned short* w2t = (unsigned short*)(ws + 7824288);  // 26,624 w
    unsigned short* wt1 = (unsigned short*)(ws + 7850912);  // 802,816 w
    // high water: 8,653,728 words = 34.6 MB

    hipMemsetAsync(bins, 0, (size_t)2560 * sizeof(int), stream);

    count_buckets<<<(E0 + E1 + 255) / 256, 256, 0, stream>>>(ei0, ei1, bins);
    prefix_scan<<<1, 256, 0, stream>>>(bins, off1, off2, cursor);
    scatter_pay<<<(E0 + E1 + 255) / 256, 256, 0, stream>>>(x, ps0, ei0, ps1, ei1,
                                                           cursor, pay1, pay2);
    w2t_prep<<<(64 * KEXT + 255) / 256, 256, 0, stream>>>(W2, root2, w2t);
    wt1_prep<<<dim3(49, 8), 256, 0, stream>>>(fc1w, wt1);
    conv1_fused<<<NB1, 256, 0, stream>>>(pay1, off1, x, W1, root1, b1, h1);
    pool1<<<(N1 * C1 + 255) / 256, 256, 0, stream>>>(h1, p1);
    conv2_fused<<<NB2, 256, 0, stream>>>(p1, pay2, off2, w2t, b2v, h2);
    pool2b<<<(112 * FC1_IN + 255) / 256, 256, 0, stream>>>(h2, p2b);
    gemm_fc1<<<dim3(8, 7, 2), 256, 0, stream>>>(p2b, wt1, z1p);
    fc2_lsm<<<BSZ, 640, 0, stream>>>(z1p, fc1b, fc2w, fc2b, (float*)d_out);
}

// Round 13
// 297.531 us; speedup vs baseline: 1.7421x; 1.7421x over previous
//
#include <hip/hip_runtime.h>
#include <hip/hip_bf16.h>

#define KK 5
constexpr int N0 = 78400;     // B*28*28
constexpr int E0 = 627200;    // N0*8
constexpr int N1 = 19600;     // B*14*14
constexpr int E1 = 156800;    // N1*8
constexpr int C1 = 32, C2 = 64;
constexpr int BSZ = 100;
constexpr int FC1_IN = 3136, FC1_OUT = 512;
constexpr int NBINS = 98000;  // N0 + N1 node-granular buckets
constexpr int KEXT = 832;     // 800 tap-space + 32 root channels
constexpr int ULS = 836;      // LDS fp32 U row stride
constexpr int CH2 = 320;      // conv2 edge staging chunk (block avg ~128)

typedef __attribute__((ext_vector_type(8))) short bf16x8;
typedef __attribute__((ext_vector_type(4))) float f32x4;

__device__ __forceinline__ unsigned short f2bf(float f) {
    union { float f; unsigned u; } v; v.f = f;
    unsigned u = v.u;
    unsigned r = (u + 0x7FFF + ((u >> 16) & 1)) >> 16;   // RNE
    return (unsigned short)r;
}

__device__ __forceinline__ void taps4(float px, float py,
                                      int& a00, int& a01, int& a10, int& a11,
                                      float& fx, float& fy) {
    float kfx = floorf(px), kfy = floorf(py);
    fx = px - kfx; fy = py - kfy;
    int k0x = min(max((int)kfx, 0), KK - 1);
    int k0y = min(max((int)kfy, 0), KK - 1);
    int k1x = min(k0x + 1, KK - 1), k1y = min(k0y + 1, KK - 1);
    a00 = k0x * KK + k0y; a01 = k0x * KK + k1y;
    a10 = k1x * KK + k0y; a11 = k1x * KK + k1y;
}

// ---- sort pass 1: node-granular histogram ----
__global__ void count_bins(const int* __restrict__ ei0, const int* __restrict__ ei1,
                           int* __restrict__ bins) {
    int gid = blockIdx.x * blockDim.x + threadIdx.x;
    if (gid < E0) {
        atomicAdd(&bins[ei0[E0 + gid]], 1);
    } else if (gid < E0 + E1) {
        atomicAdd(&bins[N0 + ei1[E1 + (gid - E0)]], 1);
    }
}

// ---- sort pass 2a: block-local exclusive scan (384 blocks x 256) ----
__global__ void scan_local(const int* __restrict__ bins, int* __restrict__ excl,
                           int* __restrict__ bsum) {
    __shared__ int tmp[256];
    int t = threadIdx.x;
    int i = blockIdx.x * 256 + t;
    int v = (i < NBINS) ? bins[i] : 0;
    tmp[t] = v;
    __syncthreads();
    for (int d = 1; d < 256; d <<= 1) {
        int add = (t >= d) ? tmp[t - d] : 0;
        __syncthreads();
        tmp[t] += add;
        __syncthreads();
    }
    if (i < NBINS) excl[i] = tmp[t] - v;
    if (t == 255) bsum[blockIdx.x] = tmp[255];
}

// ---- sort pass 2b: scan the 384 block sums (1 block x 384) ----
__global__ void scan_block(const int* __restrict__ bsum, int* __restrict__ boff) {
    __shared__ int tmp[384];
    int t = threadIdx.x;
    int v = bsum[t];
    tmp[t] = v;
    __syncthreads();
    for (int d = 1; d < 384; d <<= 1) {
        int add = (t >= d) ? tmp[t - d] : 0;
        __syncthreads();
        tmp[t] += add;
        __syncthreads();
    }
    boff[t] = tmp[t] - v;
}

// ---- sort pass 2c: final offsets + cursors ----
__global__ void fixup(const int* __restrict__ excl, const int* __restrict__ boff,
                      int* __restrict__ off, int* __restrict__ cursor) {
    int i = blockIdx.x * 256 + threadIdx.x;
    if (i < NBINS) {
        int v = excl[i] + boff[i >> 8];
        off[i] = v;
        cursor[i] = v;
    } else if (i == NBINS) {
        off[i] = E0 + E1;
    }
}

// ---- sort pass 3: scatter compact edge ids (4B each) ----
__global__ void scatter_ids(const int* __restrict__ ei0, const int* __restrict__ ei1,
                            int* __restrict__ cursor, int* __restrict__ idxx) {
    int gid = blockIdx.x * blockDim.x + threadIdx.x;
    if (gid < E0) {
        int pos = atomicAdd(&cursor[ei0[E0 + gid]], 1);
        idxx[pos] = gid;
    } else if (gid < E0 + E1) {
        int e = gid - E0;
        int pos = atomicAdd(&cursor[N0 + ei1[E1 + e]], 1);
        idxx[pos] = e;
    }
}

// ---- conv1: ONE THREAD PER NODE. Private LDS 25-tap slice, no atomics. ----
__global__ void conv1_nodes(const int* __restrict__ idxx, const int* __restrict__ off,
                            const float* __restrict__ x, const int* __restrict__ ei0,
                            const float* __restrict__ ps0, const float* __restrict__ W1,
                            const float* __restrict__ root, const float* __restrict__ bias,
                            float* __restrict__ h1) {
    __shared__ float S[256 * 25];   // 25.6 KB, stride 25 (odd) -> conflict-free
    int t = threadIdx.x;
    int n = blockIdx.x * 256 + t;
    float* sp = S + t * 25;
#pragma unroll
    for (int a = 0; a < 25; a++) sp[a] = 0.f;
    if (n >= N0) return;
    int e0 = off[n], e1 = off[n + 1];
    for (int p = e0; p < e1; p++) {
        int e = idxx[p];
        int src = ei0[e];
        int a00, a01, a10, a11; float fx, fy;
        taps4(ps0[2 * e] * (KK - 1), ps0[2 * e + 1] * (KK - 1),
              a00, a01, a10, a11, fx, fy);
        float xv = x[src];
        float gx = 1.f - fx, gy = 1.f - fy;
        sp[a00] += gx * gy * xv; sp[a01] += gx * fy * xv;
        sp[a10] += fx * gy * xv; sp[a11] += fx * fy * xv;
    }
    float s[25];
#pragma unroll
    for (int a = 0; a < 25; a++) s[a] = sp[a];
    float invd = 1.f / fmaxf((float)(e1 - e0), 1.f);
    float xn = x[n];
    for (int o = 0; o < C1; o++) {
        float acc = 0.f;
#pragma unroll
        for (int a = 0; a < 25; a++) acc += s[a] * W1[a * C1 + o];
        float v = acc * invd + xn * root[o] + bias[o];
        h1[n * C1 + o] = v > 0.f ? v : expm1f(v);
    }
}

// ---- pool1: [100,28,28,32] -> [100,14,14,32] ----
__global__ void pool1(const float* __restrict__ h1, float* __restrict__ p1) {
    int idx = blockIdx.x * blockDim.x + threadIdx.x;
    if (idx >= N1 * C1) return;
    int o = idx & 31; int t = idx >> 5;
    int c = t % 14; int r = (t / 14) % 14; int b = t / 196;
    const float* base = h1 + (((b * 28 + 2 * r) * 28 + 2 * c) * C1 + o);
    float m = fmaxf(fmaxf(base[0], base[C1]),
                    fmaxf(base[28 * C1], base[28 * C1 + C1]));
    p1[idx] = m;
}

// ---- w2t prep: bf16 transposed W2ext [64 o][832 k]; k<800 -> W2, else root2 ----
__global__ void w2t_prep(const float* __restrict__ W2, const float* __restrict__ root2,
                         unsigned short* __restrict__ w2t) {
    int idx = blockIdx.x * blockDim.x + threadIdx.x;
    if (idx >= 64 * KEXT) return;
    int o = idx / KEXT, k = idx - o * KEXT;
    float v = (k < 800) ? W2[k * 64 + o] : root2[(k - 800) * 64 + o];
    w2t[idx] = f2bf(v);
}

// ---- wt1 prep: fc1w [3136,512] fp32 -> transposed bf16 wt1[512][3136] ----
__global__ void wt1_prep(const float* __restrict__ w, unsigned short* __restrict__ wt1) {
    __shared__ unsigned short tile[64 * 66];
    int t = threadIdx.x;
    int k0 = blockIdx.x * 64, j0 = blockIdx.y * 64;
    int jj = t & 63, ks = t >> 6;
    for (int kk = ks; kk < 64; kk += 4)
        tile[kk * 66 + jj] = f2bf(w[(k0 + kk) * FC1_OUT + j0 + jj]);
    __syncthreads();
    int kk = t & 63, js = t >> 6;
    for (int j2 = js; j2 < 64; j2 += 4)
        wt1[(j0 + j2) * FC1_IN + k0 + kk] = tile[kk * 66 + j2];
}

// ---- conv2 fused (MFMA): 16 nodes/block, node-granular sorted ids.
//  Phase0: cooperative parallel staging of src/taps/fracs into LDS (no chains).
//  Phase1: group-private row RMW accumulation (NO atomics).
//  Phase2: bf16 A-pack applies 1/deg (kc<25); h2 = ELU(U@w2t^T + b2) via MFMA.
__global__ __launch_bounds__(256, 2)
void conv2_fused(const float* __restrict__ p1, const int* __restrict__ idxx,
                 const int* __restrict__ off, const int* __restrict__ ei1,
                 const float* __restrict__ ps1,
                 const unsigned short* __restrict__ w2t,
                 const float* __restrict__ b2, float* __restrict__ h2) {
    __shared__ float Ul[16 * ULS];          // 53.5 KB
    __shared__ int   es[CH2];               // src node per staged edge
    __shared__ int   et[CH2];               // 4 tap ids packed 5b each
    __shared__ float efx[CH2], efy[CH2];
    int t = threadIdx.x;
    int nb = blockIdx.x * 16;
    int i = t & 31, g = t >> 5;             // channel lane, group 0..7
    for (int nn = g; nn < 16; nn += 8) {
        float* up = Ul + nn * ULS;
#pragma unroll
        for (int a = 0; a < 25; a++) up[a * 32 + i] = 0.f;
        up[800 + i] = p1[(nb + nn) * C1 + i];
    }
    int e0 = off[N0 + nb], e1 = off[N0 + nb + 16];
    for (int base = e0; base < e1; base += CH2) {
        int nE = min(e1 - base, CH2);
        __syncthreads();
        for (int j = t; j < nE; j += 256) {
            int e = idxx[base + j];
            es[j] = ei1[e];
            int a00, a01, a10, a11; float fx, fy;
            taps4(ps1[2 * e] * (KK - 1), ps1[2 * e + 1] * (KK - 1),
                  a00, a01, a10, a11, fx, fy);
            et[j] = a00 | (a01 << 5) | (a10 << 10) | (a11 << 15);
            efx[j] = fx; efy[j] = fy;
        }
        __syncthreads();
        for (int nn = g; nn < 16; nn += 8) {
            int r0 = max(off[N0 + nb + nn] - base, 0);
            int r1 = min(off[N0 + nb + nn + 1] - base, nE);
            float* up = Ul + nn * ULS;
#pragma unroll 2
            for (int j = r0; j < r1; j++) {
                int src = es[j]; int m = et[j];
                float fx = efx[j], fy = efy[j];
                float xv = p1[src * C1 + i];    // coalesced 128B per group
                float gx = 1.f - fx, gy = 1.f - fy;
                up[(m & 31) * 32 + i]         += gx * gy * xv;
                up[((m >> 5) & 31) * 32 + i]  += gx * fy * xv;
                up[((m >> 10) & 31) * 32 + i] += fx * gy * xv;
                up[((m >> 15) & 31) * 32 + i] += fx * fy * xv;
            }
        }
    }
    __syncthreads();
    // phase 2: MFMA. wave wv -> o-tile. D[node=quad*4+r][o=lane&15]
    int wv = t >> 6, lane = t & 63, quad = lane >> 4, lrow = lane & 15;
    f32x4 acc = {0.f, 0.f, 0.f, 0.f};
    int dg = off[N0 + nb + lrow + 1] - off[N0 + nb + lrow];
    float invd = 1.f / fmaxf((float)dg, 1.f);
    const unsigned short* bbase = w2t + (wv * 16 + lrow) * KEXT;
    const float* abase = Ul + lrow * ULS;
#pragma unroll
    for (int kc = 0; kc < 26; kc++) {
        float4 a0 = *(const float4*)(abase + kc * 32 + quad * 8);
        float4 a1 = *(const float4*)(abase + kc * 32 + quad * 8 + 4);
        float s = (kc < 25) ? invd : 1.f;
        bf16x8 a;
        a[0] = (short)f2bf(a0.x * s); a[1] = (short)f2bf(a0.y * s);
        a[2] = (short)f2bf(a0.z * s); a[3] = (short)f2bf(a0.w * s);
        a[4] = (short)f2bf(a1.x * s); a[5] = (short)f2bf(a1.y * s);
        a[6] = (short)f2bf(a1.z * s); a[7] = (short)f2bf(a1.w * s);
        bf16x8 b = *(const bf16x8*)(bbase + kc * 32 + quad * 8);
        acc = __builtin_amdgcn_mfma_f32_16x16x32_bf16(a, b, acc, 0, 0, 0);
    }
    int o = wv * 16 + lrow;
    float bo = b2[o];
#pragma unroll
    for (int r = 0; r < 4; r++) {
        int node = quad * 4 + r;
        float v = acc[r] + bo;
        v = v > 0.f ? v : expm1f(v);
        h2[(nb + node) * C2 + o] = v;
    }
}

// ---- pool2 -> bf16 [112 x 3136], rows 100..111 zeroed (M-pad for MFMA) ----
__global__ void pool2b(const float* __restrict__ h2, unsigned short* __restrict__ p2b) {
    int idx = blockIdx.x * blockDim.x + threadIdx.x;
    if (idx >= 112 * FC1_IN) return;
    if (idx >= 100 * FC1_IN) { p2b[idx] = 0; return; }
    int o = idx & 63; int t2 = idx >> 6;
    int c = t2 % 14; int r = (t2 / 14) % 14; int b = t2 / 196;
    const float* base = h2 + (((b * 28 + 2 * r) * 28 + 2 * c) * C2 + o);
    float m = fmaxf(fmaxf(base[0], base[C2]),
                    fmaxf(base[28 * C2], base[28 * C2 + C2]));
    p2b[idx] = f2bf(m);
}

// ---- fc1 MFMA: [112,3136]bf16 @ wt1^T -> z1p fp32 partials (2 kz). ----
__global__ void gemm_fc1(const unsigned short* __restrict__ p2b,
                         const unsigned short* __restrict__ wt1,
                         float* __restrict__ z1p) {
    constexpr int AS = 232;              // 224 + 8 pad, 16B aligned
    __shared__ unsigned short as_[16 * AS];   // 7.4 KB
    int t = threadIdx.x;
    int jt = blockIdx.x, mt = blockIdx.y, kz = blockIdx.z;
    int wv = t >> 6, lane = t & 63, quad = lane >> 4, lrow = lane & 15;
    int m0 = mt * 16;
    int kbase = kz * 1568;
    const unsigned short* bbase = wt1 + (jt * 64 + wv * 16 + lrow) * FC1_IN + kbase;
    f32x4 acc = {0.f, 0.f, 0.f, 0.f};
    for (int ch = 0; ch < 7; ch++) {
        __syncthreads();
        for (int slot = t; slot < 448; slot += 256) {   // 16 rows x 28 uint4
            int r = slot / 28, c = slot - (slot / 28) * 28;
            *(uint4*)(as_ + r * AS + c * 8) =
                *(const uint4*)(p2b + (m0 + r) * FC1_IN + kbase + ch * 224 + c * 8);
        }
        __syncthreads();
        const unsigned short* ab = as_ + lrow * AS;
        const unsigned short* bb = bbase + ch * 224;
#pragma unroll
        for (int kk = 0; kk < 7; kk++) {
            bf16x8 a = *(const bf16x8*)(ab + kk * 32 + quad * 8);
            bf16x8 b = *(const bf16x8*)(bb + kk * 32 + quad * 8);
            acc = __builtin_amdgcn_mfma_f32_16x16x32_bf16(a, b, acc, 0, 0, 0);
        }
    }
    int n = jt * 64 + wv * 16 + lrow;
#pragma unroll
    for (int r = 0; r < 4; r++) {
        int m = m0 + quad * 4 + r;
        z1p[kz * (112 * FC1_OUT) + m * FC1_OUT + n] = acc[r];
    }
}

// ---- fc2 + log_softmax fused; sums 2 fc1 partials, applies fc1 bias+ELU ----
__global__ void fc2_lsm(const float* __restrict__ z1p, const float* __restrict__ fc1b,
                        const float* __restrict__ w, const float* __restrict__ fc2b,
                        float* __restrict__ out) {
    int b = blockIdx.x;
    int t = threadIdx.x;
    int wv = t >> 6;
    int lane = t & 63;
    float acc = 0.f;
#pragma unroll
    for (int m = 0; m < 8; m++) {
        int k = lane * 8 + m;
        float xv = fc1b[k] + z1p[b * FC1_OUT + k] + z1p[112 * FC1_OUT + b * FC1_OUT + k];
        xv = xv > 0.f ? xv : expm1f(xv);
        acc += xv * w[k * 10 + wv];
    }
#pragma unroll
    for (int off = 32; off > 0; off >>= 1) acc += __shfl_down(acc, off);
    __shared__ float zs[10];
    if (lane == 0) {
        float z = acc + fc2b[wv];
        zs[wv] = z > 0.f ? z : expm1f(z);
    }
    __syncthreads();
    if (t < 10) {
        float m = -1e30f;
        for (int jj = 0; jj < 10; jj++) m = fmaxf(m, zs[jj]);
        float s = 0.f;
        for (int jj = 0; jj < 10; jj++) s += expf(zs[jj] - m);
        out[b * 10 + t] = zs[t] - m - logf(s);
    }
}

extern "C" void kernel_launch(void* const* d_in, const int* in_sizes, int n_in,
                              void* d_out, int out_size, void* d_ws, size_t ws_size,
                              hipStream_t stream) {
    const float* x     = (const float*)d_in[0];
    const float* ps0   = (const float*)d_in[1];
    const float* ps1   = (const float*)d_in[2];
    const float* W1    = (const float*)d_in[3];
    const float* root1 = (const float*)d_in[4];
    const float* b1    = (const float*)d_in[5];
    const float* W2    = (const float*)d_in[6];
    const float* root2 = (const float*)d_in[7];
    const float* b2v   = (const float*)d_in[8];
    const float* fc1w  = (const float*)d_in[9];
    const float* fc1b  = (const float*)d_in[10];
    const float* fc2w  = (const float*)d_in[11];
    const float* fc2b  = (const float*)d_in[12];
    const int*   ei0   = (const int*)d_in[13];
    const int*   ei1   = (const int*)d_in[14];

    float* ws = (float*)d_ws;
    int* bins   = (int*)ws;                        //     98,000  (memset region)
    int* excl   = (int*)(ws + 98000);              //     98,000
    int* bsum   = (int*)(ws + 196000);             //        384
    int* boff   = (int*)(ws + 196384);             //        384
    int* off    = (int*)(ws + 196768);             //     98,001
    int* cursor = (int*)(ws + 294772);             //     98,000
    int* idxx   = (int*)(ws + 392772);             //    784,000
    float* h1   = ws + 1176772;                    //  2,508,800
    float* p1   = ws + 3685572;                    //    627,200
    float* h2   = ws + 4312772;                    //  1,254,400
    unsigned short* p2b = (unsigned short*)(ws + 5567172);  // 175,616 w
    float* z1p  = ws + 5742788;                    //    114,688
    unsigned short* w2t = (unsigned short*)(ws + 5857476);  // 26,624 w
    unsigned short* wt1 = (unsigned short*)(ws + 5884100);  // 802,816 w
    // high water: 6,686,916 words = 26.7 MB

    hipMemsetAsync(bins, 0, (size_t)NBINS * sizeof(int), stream);

    count_bins<<<(E0 + E1 + 255) / 256, 256, 0, stream>>>(ei0, ei1, bins);
    scan_local<<<384, 256, 0, stream>>>(bins, excl, bsum);
    scan_block<<<1, 384, 0, stream>>>(bsum, boff);
    fixup<<<384, 256, 0, stream>>>(excl, boff, off, cursor);
    scatter_ids<<<(E0 + E1 + 255) / 256, 256, 0, stream>>>(ei0, ei1, cursor, idxx);
    w2t_prep<<<(64 * KEXT + 255) / 256, 256, 0, stream>>>(W2, root2, w2t);
    wt1_prep<<<dim3(49, 8), 256, 0, stream>>>(fc1w, wt1);
    conv1_nodes<<<(N0 + 255) / 256, 256, 0, stream>>>(idxx, off, x, ei0, ps0,
                                                      W1, root1, b1, h1);
    pool1<<<(N1 * C1 + 255) / 256, 256, 0, stream>>>(h1, p1);
    conv2_fused<<<N1 / 16, 256, 0, stream>>>(p1, idxx, off, ei1, ps1, w2t, b2v, h2);
    pool2b<<<(112 * FC1_IN + 255) / 256, 256, 0, stream>>>(h2, p2b);
    gemm_fc1<<<dim3(8, 7, 2), 256, 0, stream>>>(p2b, wt1, z1p);
    fc2_lsm<<<BSZ, 640, 0, stream>>>(z1p, fc1b, fc2w, fc2b, (float*)d_out);
}

// Round 14
// 236.768 us; speedup vs baseline: 2.1892x; 1.2566x over previous
//
#include <hip/hip_runtime.h>
#include <hip/hip_bf16.h>

#define KK 5
constexpr int N0 = 78400;     // B*28*28
constexpr int E0 = 627200;    // N0*8
constexpr int N1 = 19600;     // B*14*14
constexpr int E1 = 156800;    // N1*8
constexpr int C1 = 32, C2 = 64;
constexpr int BSZ = 100;
constexpr int FC1_IN = 3136, FC1_OUT = 512;
constexpr int NKEYS = 98000;  // N0 + N1 global node keys
constexpr int NCOARSE = 383;  // coarse buckets of 256 keys
constexpr int CAPB = 2400;    // bucket capacity: Poisson(2048) + 7.7 sigma
constexpr int KEXT = 832;     // 800 tap-space + 32 root channels
constexpr int ULS = 836;      // LDS fp32 U row stride
constexpr int CH2 = 320;      // conv2 edge staging chunk

typedef __attribute__((ext_vector_type(8))) short bf16x8;
typedef __attribute__((ext_vector_type(4))) float f32x4;

__device__ __forceinline__ unsigned short f2bf(float f) {
    union { float f; unsigned u; } v; v.f = f;
    unsigned u = v.u;
    unsigned r = (u + 0x7FFF + ((u >> 16) & 1)) >> 16;   // RNE
    return (unsigned short)r;
}

__device__ __forceinline__ void taps4(float px, float py,
                                      int& a00, int& a01, int& a10, int& a11,
                                      float& fx, float& fy) {
    float kfx = floorf(px), kfy = floorf(py);
    fx = px - kfx; fy = py - kfy;
    int k0x = min(max((int)kfx, 0), KK - 1);
    int k0y = min(max((int)kfy, 0), KK - 1);
    int k1x = min(k0x + 1, KK - 1), k1y = min(k0y + 1, KK - 1);
    a00 = k0x * KK + k0y; a01 = k0x * KK + k1y;
    a10 = k1x * KK + k0y; a11 = k1x * KK + k1y;
}

// ---- sort A: LDS-histogram coarse binning; packed {id | lowkey<<20} runs ----
__global__ void coarse_bin(const int* __restrict__ ei0, const int* __restrict__ ei1,
                           int* __restrict__ gcur, int* __restrict__ pk) {
    __shared__ int hist[NCOARSE];
    __shared__ int gbase[NCOARSE];
    int t = threadIdx.x;               // 512 threads
    for (int i = t; i < NCOARSE; i += 512) hist[i] = 0;
    __syncthreads();
    int e0b = blockIdx.x * 4096;
    int ids[8], keys[8], rnk[8];
#pragma unroll
    for (int j = 0; j < 8; j++) {
        int e = e0b + t + j * 512;
        int gk = -1, id = 0;
        if (e < E0) { gk = ei0[E0 + e]; id = e; }
        else if (e < E0 + E1) { int el = e - E0; gk = N0 + ei1[E1 + el]; id = el; }
        ids[j] = id; keys[j] = gk;
    }
#pragma unroll
    for (int j = 0; j < 8; j++)
        if (keys[j] >= 0) rnk[j] = atomicAdd(&hist[keys[j] >> 8], 1);  // native ds_add
    __syncthreads();
    for (int i = t; i < NCOARSE; i += 512)
        gbase[i] = hist[i] ? atomicAdd(&gcur[i], hist[i]) : 0;
    __syncthreads();
#pragma unroll
    for (int j = 0; j < 8; j++) {
        if (keys[j] >= 0) {
            int b = keys[j] >> 8;
            int p = gbase[b] + rnk[j];
            if (p < CAPB) pk[b * CAPB + p] = ids[j] | ((keys[j] & 255) << 20);
        }
    }
}

// ---- sort B: scan 383 bucket counts -> dense bases ----
__global__ void tiny_scan(const int* __restrict__ gcur, int* __restrict__ db,
                          int* __restrict__ off) {
    __shared__ int tmp[NCOARSE];
    int t = threadIdx.x;   // 512
    if (t < NCOARSE) tmp[t] = min(gcur[t], CAPB);
    __syncthreads();
    if (t == 0) {
        int s = 0;
        for (int i = 0; i < NCOARSE; i++) { int c = tmp[i]; tmp[i] = s; s += c; }
    }
    __syncthreads();
    if (t < NCOARSE) db[t] = tmp[t];
    if (t == 0) off[NKEYS] = E0 + E1;
}

// ---- sort C: per-bucket LDS counting sort -> dense idxx + off ----
__global__ void fine_sort(const int* __restrict__ pk, const int* __restrict__ gcur,
                          const int* __restrict__ db,
                          int* __restrict__ idxx, int* __restrict__ off) {
    __shared__ int ent[CAPB];      // 9.6 KB
    __shared__ int rnk[CAPB];      // 9.6 KB
    __shared__ int h2[256];
    __shared__ int sc[256];
    int b = blockIdx.x, t = threadIdx.x;   // 256 threads
    int cb = min(gcur[b], CAPB);
    int base = db[b];
    h2[t] = 0;
    __syncthreads();
    for (int i = t; i < cb; i += 256) {
        int v = pk[b * CAPB + i];
        ent[i] = v;
        rnk[i] = atomicAdd(&h2[(v >> 20) & 255], 1);   // native ds_add
    }
    __syncthreads();
    // exclusive scan of h2 into sc
    int v0 = h2[t];
    sc[t] = v0;
    __syncthreads();
    for (int d = 1; d < 256; d <<= 1) {
        int add = (t >= d) ? sc[t - d] : 0;
        __syncthreads();
        sc[t] += add;
        __syncthreads();
    }
    int excl = sc[t] - v0;
    __syncthreads();
    sc[t] = excl;
    __syncthreads();
    int n = (b << 8) + t;
    if (n < NKEYS) off[n] = base + excl;
    for (int i = t; i < cb; i += 256) {
        int v = ent[i];
        idxx[base + sc[(v >> 20) & 255] + rnk[i]] = v & 0xFFFFF;
    }
}

// ---- conv1: ONE THREAD PER NODE. Private LDS 25-tap slice, no atomics. ----
__global__ void conv1_nodes(const int* __restrict__ idxx, const int* __restrict__ off,
                            const float* __restrict__ x, const int* __restrict__ ei0,
                            const float* __restrict__ ps0, const float* __restrict__ W1,
                            const float* __restrict__ root, const float* __restrict__ bias,
                            float* __restrict__ h1) {
    __shared__ float S[256 * 25];   // 25.6 KB, stride 25 (odd) -> conflict-free
    int t = threadIdx.x;
    int n = blockIdx.x * 256 + t;
    float* sp = S + t * 25;
#pragma unroll
    for (int a = 0; a < 25; a++) sp[a] = 0.f;
    if (n >= N0) return;
    int e0 = off[n], e1 = off[n + 1];
    for (int p = e0; p < e1; p++) {
        int e = idxx[p];
        int src = ei0[e];
        int a00, a01, a10, a11; float fx, fy;
        taps4(ps0[2 * e] * (KK - 1), ps0[2 * e + 1] * (KK - 1),
              a00, a01, a10, a11, fx, fy);
        float xv = x[src];
        float gx = 1.f - fx, gy = 1.f - fy;
        sp[a00] += gx * gy * xv; sp[a01] += gx * fy * xv;
        sp[a10] += fx * gy * xv; sp[a11] += fx * fy * xv;
    }
    float s[25];
#pragma unroll
    for (int a = 0; a < 25; a++) s[a] = sp[a];
    float invd = 1.f / fmaxf((float)(e1 - e0), 1.f);
    float xn = x[n];
    for (int o = 0; o < C1; o++) {
        float acc = 0.f;
#pragma unroll
        for (int a = 0; a < 25; a++) acc += s[a] * W1[a * C1 + o];
        float v = acc * invd + xn * root[o] + bias[o];
        h1[n * C1 + o] = v > 0.f ? v : expm1f(v);
    }
}

// ---- pool1: [100,28,28,32] -> [100,14,14,32] ----
__global__ void pool1(const float* __restrict__ h1, float* __restrict__ p1) {
    int idx = blockIdx.x * blockDim.x + threadIdx.x;
    if (idx >= N1 * C1) return;
    int o = idx & 31; int t = idx >> 5;
    int c = t % 14; int r = (t / 14) % 14; int b = t / 196;
    const float* base = h1 + (((b * 28 + 2 * r) * 28 + 2 * c) * C1 + o);
    float m = fmaxf(fmaxf(base[0], base[C1]),
                    fmaxf(base[28 * C1], base[28 * C1 + C1]));
    p1[idx] = m;
}

// ---- w2t prep: bf16 transposed W2ext [64 o][832 k]; k<800 -> W2, else root2 ----
__global__ void w2t_prep(const float* __restrict__ W2, const float* __restrict__ root2,
                         unsigned short* __restrict__ w2t) {
    int idx = blockIdx.x * blockDim.x + threadIdx.x;
    if (idx >= 64 * KEXT) return;
    int o = idx / KEXT, k = idx - o * KEXT;
    float v = (k < 800) ? W2[k * 64 + o] : root2[(k - 800) * 64 + o];
    w2t[idx] = f2bf(v);
}

// ---- wt1 prep: fc1w [3136,512] fp32 -> transposed bf16 wt1[512][3136] ----
__global__ void wt1_prep(const float* __restrict__ w, unsigned short* __restrict__ wt1) {
    __shared__ unsigned short tile[64 * 66];
    int t = threadIdx.x;
    int k0 = blockIdx.x * 64, j0 = blockIdx.y * 64;
    int jj = t & 63, ks = t >> 6;
    for (int kk = ks; kk < 64; kk += 4)
        tile[kk * 66 + jj] = f2bf(w[(k0 + kk) * FC1_OUT + j0 + jj]);
    __syncthreads();
    int kk = t & 63, js = t >> 6;
    for (int j2 = js; j2 < 64; j2 += 4)
        wt1[(j0 + j2) * FC1_IN + k0 + kk] = tile[kk * 66 + j2];
}

// ---- conv2 fused (MFMA): 16 nodes/block, node-sorted ids.
//  Phase0: cooperative parallel staging of src/taps/fracs into LDS.
//  Phase1: group-private row RMW accumulation (NO atomics).
//  Phase2: bf16 A-pack applies 1/deg (kc<25); h2 = ELU(U@w2t^T + b2) via MFMA.
__global__ __launch_bounds__(256, 2)
void conv2_fused(const float* __restrict__ p1, const int* __restrict__ idxx,
                 const int* __restrict__ off, const int* __restrict__ ei1,
                 const float* __restrict__ ps1,
                 const unsigned short* __restrict__ w2t,
                 const float* __restrict__ b2, float* __restrict__ h2) {
    __shared__ float Ul[16 * ULS];          // 53.5 KB
    __shared__ int   es[CH2];
    __shared__ int   et[CH2];
    __shared__ float efx[CH2], efy[CH2];
    int t = threadIdx.x;
    int nb = blockIdx.x * 16;
    int i = t & 31, g = t >> 5;             // channel lane, group 0..7
    for (int nn = g; nn < 16; nn += 8) {
        float* up = Ul + nn * ULS;
#pragma unroll
        for (int a = 0; a < 25; a++) up[a * 32 + i] = 0.f;
        up[800 + i] = p1[(nb + nn) * C1 + i];
    }
    int e0 = off[N0 + nb], e1 = off[N0 + nb + 16];
    for (int base = e0; base < e1; base += CH2) {
        int nE = min(e1 - base, CH2);
        __syncthreads();
        for (int j = t; j < nE; j += 256) {
            int e = idxx[base + j];
            es[j] = ei1[e];
            int a00, a01, a10, a11; float fx, fy;
            taps4(ps1[2 * e] * (KK - 1), ps1[2 * e + 1] * (KK - 1),
                  a00, a01, a10, a11, fx, fy);
            et[j] = a00 | (a01 << 5) | (a10 << 10) | (a11 << 15);
            efx[j] = fx; efy[j] = fy;
        }
        __syncthreads();
        for (int nn = g; nn < 16; nn += 8) {
            int r0 = max(off[N0 + nb + nn] - base, 0);
            int r1 = min(off[N0 + nb + nn + 1] - base, nE);
            float* up = Ul + nn * ULS;
#pragma unroll 2
            for (int j = r0; j < r1; j++) {
                int src = es[j]; int m = et[j];
                float fx = efx[j], fy = efy[j];
                float xv = p1[src * C1 + i];
                float gx = 1.f - fx, gy = 1.f - fy;
                up[(m & 31) * 32 + i]         += gx * gy * xv;
                up[((m >> 5) & 31) * 32 + i]  += gx * fy * xv;
                up[((m >> 10) & 31) * 32 + i] += fx * gy * xv;
                up[((m >> 15) & 31) * 32 + i] += fx * fy * xv;
            }
        }
    }
    __syncthreads();
    int wv = t >> 6, lane = t & 63, quad = lane >> 4, lrow = lane & 15;
    f32x4 acc = {0.f, 0.f, 0.f, 0.f};
    int dg = off[N0 + nb + lrow + 1] - off[N0 + nb + lrow];
    float invd = 1.f / fmaxf((float)dg, 1.f);
    const unsigned short* bbase = w2t + (wv * 16 + lrow) * KEXT;
    const float* abase = Ul + lrow * ULS;
#pragma unroll
    for (int kc = 0; kc < 26; kc++) {
        float4 a0 = *(const float4*)(abase + kc * 32 + quad * 8);
        float4 a1 = *(const float4*)(abase + kc * 32 + quad * 8 + 4);
        float s = (kc < 25) ? invd : 1.f;
        bf16x8 a;
        a[0] = (short)f2bf(a0.x * s); a[1] = (short)f2bf(a0.y * s);
        a[2] = (short)f2bf(a0.z * s); a[3] = (short)f2bf(a0.w * s);
        a[4] = (short)f2bf(a1.x * s); a[5] = (short)f2bf(a1.y * s);
        a[6] = (short)f2bf(a1.z * s); a[7] = (short)f2bf(a1.w * s);
        bf16x8 b = *(const bf16x8*)(bbase + kc * 32 + quad * 8);
        acc = __builtin_amdgcn_mfma_f32_16x16x32_bf16(a, b, acc, 0, 0, 0);
    }
    int o = wv * 16 + lrow;
    float bo = b2[o];
#pragma unroll
    for (int r = 0; r < 4; r++) {
        int node = quad * 4 + r;
        float v = acc[r] + bo;
        v = v > 0.f ? v : expm1f(v);
        h2[(nb + node) * C2 + o] = v;
    }
}

// ---- pool2 -> bf16 [112 x 3136], rows 100..111 zeroed (M-pad for MFMA) ----
__global__ void pool2b(const float* __restrict__ h2, unsigned short* __restrict__ p2b) {
    int idx = blockIdx.x * blockDim.x + threadIdx.x;
    if (idx >= 112 * FC1_IN) return;
    if (idx >= 100 * FC1_IN) { p2b[idx] = 0; return; }
    int o = idx & 63; int t2 = idx >> 6;
    int c = t2 % 14; int r = (t2 / 14) % 14; int b = t2 / 196;
    const float* base = h2 + (((b * 28 + 2 * r) * 28 + 2 * c) * C2 + o);
    float m = fmaxf(fmaxf(base[0], base[C2]),
                    fmaxf(base[28 * C2], base[28 * C2 + C2]));
    p2b[idx] = f2bf(m);
}

// ---- fc1 MFMA: [112,3136]bf16 @ wt1^T -> z1p fp32 partials (2 kz). ----
__global__ void gemm_fc1(const unsigned short* __restrict__ p2b,
                         const unsigned short* __restrict__ wt1,
                         float* __restrict__ z1p) {
    constexpr int AS = 232;              // 224 + 8 pad, 16B aligned
    __shared__ unsigned short as_[16 * AS];   // 7.4 KB
    int t = threadIdx.x;
    int jt = blockIdx.x, mt = blockIdx.y, kz = blockIdx.z;
    int wv = t >> 6, lane = t & 63, quad = lane >> 4, lrow = lane & 15;
    int m0 = mt * 16;
    int kbase = kz * 1568;
    const unsigned short* bbase = wt1 + (jt * 64 + wv * 16 + lrow) * FC1_IN + kbase;
    f32x4 acc = {0.f, 0.f, 0.f, 0.f};
    for (int ch = 0; ch < 7; ch++) {
        __syncthreads();
        for (int slot = t; slot < 448; slot += 256) {   // 16 rows x 28 uint4
            int r = slot / 28, c = slot - (slot / 28) * 28;
            *(uint4*)(as_ + r * AS + c * 8) =
                *(const uint4*)(p2b + (m0 + r) * FC1_IN + kbase + ch * 224 + c * 8);
        }
        __syncthreads();
        const unsigned short* ab = as_ + lrow * AS;
        const unsigned short* bb = bbase + ch * 224;
#pragma unroll
        for (int kk = 0; kk < 7; kk++) {
            bf16x8 a = *(const bf16x8*)(ab + kk * 32 + quad * 8);
            bf16x8 b = *(const bf16x8*)(bb + kk * 32 + quad * 8);
            acc = __builtin_amdgcn_mfma_f32_16x16x32_bf16(a, b, acc, 0, 0, 0);
        }
    }
    int n = jt * 64 + wv * 16 + lrow;
#pragma unroll
    for (int r = 0; r < 4; r++) {
        int m = m0 + quad * 4 + r;
        z1p[kz * (112 * FC1_OUT) + m * FC1_OUT + n] = acc[r];
    }
}

// ---- fc2 + log_softmax fused; sums 2 fc1 partials, applies fc1 bias+ELU ----
__global__ void fc2_lsm(const float* __restrict__ z1p, const float* __restrict__ fc1b,
                        const float* __restrict__ w, const float* __restrict__ fc2b,
                        float* __restrict__ out) {
    int b = blockIdx.x;
    int t = threadIdx.x;
    int wv = t >> 6;
    int lane = t & 63;
    float acc = 0.f;
#pragma unroll
    for (int m = 0; m < 8; m++) {
        int k = lane * 8 + m;
        float xv = fc1b[k] + z1p[b * FC1_OUT + k] + z1p[112 * FC1_OUT + b * FC1_OUT + k];
        xv = xv > 0.f ? xv : expm1f(xv);
        acc += xv * w[k * 10 + wv];
    }
#pragma unroll
    for (int off = 32; off > 0; off >>= 1) acc += __shfl_down(acc, off);
    __shared__ float zs[10];
    if (lane == 0) {
        float z = acc + fc2b[wv];
        zs[wv] = z > 0.f ? z : expm1f(z);
    }
    __syncthreads();
    if (t < 10) {
        float m = -1e30f;
        for (int jj = 0; jj < 10; jj++) m = fmaxf(m, zs[jj]);
        float s = 0.f;
        for (int jj = 0; jj < 10; jj++) s += expf(zs[jj] - m);
        out[b * 10 + t] = zs[t] - m - logf(s);
    }
}

extern "C" void kernel_launch(void* const* d_in, const int* in_sizes, int n_in,
                              void* d_out, int out_size, void* d_ws, size_t ws_size,
                              hipStream_t stream) {
    const float* x     = (const float*)d_in[0];
    const float* ps0   = (const float*)d_in[1];
    const float* ps1   = (const float*)d_in[2];
    const float* W1    = (const float*)d_in[3];
    const float* root1 = (const float*)d_in[4];
    const float* b1    = (const float*)d_in[5];
    const float* W2    = (const float*)d_in[6];
    const float* root2 = (const float*)d_in[7];
    const float* b2v   = (const float*)d_in[8];
    const float* fc1w  = (const float*)d_in[9];
    const float* fc1b  = (const float*)d_in[10];
    const float* fc2w  = (const float*)d_in[11];
    const float* fc2b  = (const float*)d_in[12];
    const int*   ei0   = (const int*)d_in[13];
    const int*   ei1   = (const int*)d_in[14];

    float* ws = (float*)d_ws;
    int* gcur  = (int*)ws;                         //        383  (memset region)
    int* db    = (int*)(ws + 384);                 //        383
    int* off   = (int*)(ws + 768);                 //     98,001
    int* pk    = (int*)(ws + 98772);               //    919,200 (383 x 2400)
    int* idxx  = (int*)(ws + 1017972);             //    784,000
    float* h1  = ws + 1801972;                     //  2,508,800
    float* p1  = ws + 4310772;                     //    627,200
    float* h2  = ws + 4937972;                     //  1,254,400
    unsigned short* p2b = (unsigned short*)(ws + 6192372);  // 175,616 w
    float* z1p = ws + 6367988;                     //    114,688
    unsigned short* w2t = (unsigned short*)(ws + 6482676);  // 26,624 w
    unsigned short* wt1 = (unsigned short*)(ws + 6509300);  // 802,816 w
    // high water: 7,312,116 words = 29.2 MB

    hipMemsetAsync(gcur, 0, (size_t)NCOARSE * sizeof(int), stream);

    coarse_bin<<<(E0 + E1 + 4095) / 4096, 512, 0, stream>>>(ei0, ei1, gcur, pk);
    tiny_scan<<<1, 512, 0, stream>>>(gcur, db, off);
    fine_sort<<<NCOARSE, 256, 0, stream>>>(pk, gcur, db, idxx, off);
    w2t_prep<<<(64 * KEXT + 255) / 256, 256, 0, stream>>>(W2, root2, w2t);
    wt1_prep<<<dim3(49, 8), 256, 0, stream>>>(fc1w, wt1);
    conv1_nodes<<<(N0 + 255) / 256, 256, 0, stream>>>(idxx, off, x, ei0, ps0,
                                                      W1, root1, b1, h1);
    pool1<<<(N1 * C1 + 255) / 256, 256, 0, stream>>>(h1, p1);
    conv2_fused<<<N1 / 16, 256, 0, stream>>>(p1, idxx, off, ei1, ps1, w2t, b2v, h2);
    pool2b<<<(112 * FC1_IN + 255) / 256, 256, 0, stream>>>(h2, p2b);
    gemm_fc1<<<dim3(8, 7, 2), 256, 0, stream>>>(p2b, wt1, z1p);
    fc2_lsm<<<BSZ, 640, 0, stream>>>(z1p, fc1b, fc2w, fc2b, (float*)d_out);
}

// Round 15
// 223.320 us; speedup vs baseline: 2.3211x; 1.0602x over previous
//
#include <hip/hip_runtime.h>
#include <hip/hip_bf16.h>

#define KK 5
constexpr int N0 = 78400;     // B*28*28
constexpr int E0 = 627200;    // N0*8
constexpr int N1 = 19600;     // B*14*14
constexpr int E1 = 156800;    // N1*8
constexpr int C1 = 32, C2 = 64;
constexpr int BSZ = 100;
constexpr int FC1_IN = 3136, FC1_OUT = 512;
constexpr int NKEYS = 98000;  // N0 + N1 global node keys
constexpr int NCOARSE = 383;  // coarse buckets of 256 keys
constexpr int CAPB = 2400;    // bucket capacity: Poisson(2048) + 7.7 sigma
constexpr int KEXT = 832;     // 800 tap-space + 32 root channels
constexpr int ULS = 836;      // LDS fp32 U row stride
constexpr int CH2 = 160;      // conv2 edge staging chunk (block avg ~64)

typedef __attribute__((ext_vector_type(8))) short bf16x8;
typedef __attribute__((ext_vector_type(4))) float f32x4;

__device__ __forceinline__ unsigned short f2bf(float f) {
    union { float f; unsigned u; } v; v.f = f;
    unsigned u = v.u;
    unsigned r = (u + 0x7FFF + ((u >> 16) & 1)) >> 16;   // RNE
    return (unsigned short)r;
}

__device__ __forceinline__ void taps4(float px, float py,
                                      int& a00, int& a01, int& a10, int& a11,
                                      float& fx, float& fy) {
    float kfx = floorf(px), kfy = floorf(py);
    fx = px - kfx; fy = py - kfy;
    int k0x = min(max((int)kfx, 0), KK - 1);
    int k0y = min(max((int)kfy, 0), KK - 1);
    int k1x = min(k0x + 1, KK - 1), k1y = min(k0y + 1, KK - 1);
    a00 = k0x * KK + k0y; a01 = k0x * KK + k1y;
    a10 = k1x * KK + k0y; a11 = k1x * KK + k1y;
}

// ---- sort A: LDS-histogram coarse binning; packed {id | lowkey<<20} runs ----
__global__ void coarse_bin(const int* __restrict__ ei0, const int* __restrict__ ei1,
                           int* __restrict__ gcur, int* __restrict__ pk) {
    __shared__ int hist[NCOARSE];
    __shared__ int gbase[NCOARSE];
    int t = threadIdx.x;               // 512 threads
    for (int i = t; i < NCOARSE; i += 512) hist[i] = 0;
    __syncthreads();
    int e0b = blockIdx.x * 4096;
    int ids[8], keys[8], rnk[8];
#pragma unroll
    for (int j = 0; j < 8; j++) {
        int e = e0b + t + j * 512;
        int gk = -1, id = 0;
        if (e < E0) { gk = ei0[E0 + e]; id = e; }
        else if (e < E0 + E1) { int el = e - E0; gk = N0 + ei1[E1 + el]; id = el; }
        ids[j] = id; keys[j] = gk;
    }
#pragma unroll
    for (int j = 0; j < 8; j++)
        if (keys[j] >= 0) rnk[j] = atomicAdd(&hist[keys[j] >> 8], 1);  // native ds_add
    __syncthreads();
    for (int i = t; i < NCOARSE; i += 512)
        gbase[i] = hist[i] ? atomicAdd(&gcur[i], hist[i]) : 0;
    __syncthreads();
#pragma unroll
    for (int j = 0; j < 8; j++) {
        if (keys[j] >= 0) {
            int b = keys[j] >> 8;
            int p = gbase[b] + rnk[j];
            if (p < CAPB) pk[b * CAPB + p] = ids[j] | ((keys[j] & 255) << 20);
        }
    }
}

// ---- sort B: scan 383 bucket counts -> dense bases ----
__global__ void tiny_scan(const int* __restrict__ gcur, int* __restrict__ db,
                          int* __restrict__ off) {
    __shared__ int tmp[NCOARSE];
    int t = threadIdx.x;   // 512
    if (t < NCOARSE) tmp[t] = min(gcur[t], CAPB);
    __syncthreads();
    if (t == 0) {
        int s = 0;
        for (int i = 0; i < NCOARSE; i++) { int c = tmp[i]; tmp[i] = s; s += c; }
    }
    __syncthreads();
    if (t < NCOARSE) db[t] = tmp[t];
    if (t == 0) off[NKEYS] = E0 + E1;
}

// ---- sort C: per-bucket LDS counting sort -> dense idxx + off ----
__global__ void fine_sort(const int* __restrict__ pk, const int* __restrict__ gcur,
                          const int* __restrict__ db,
                          int* __restrict__ idxx, int* __restrict__ off) {
    __shared__ int ent[CAPB];      // 9.6 KB
    __shared__ int rnk[CAPB];      // 9.6 KB
    __shared__ int h2[256];
    __shared__ int sc[256];
    int b = blockIdx.x, t = threadIdx.x;   // 256 threads
    int cb = min(gcur[b], CAPB);
    int base = db[b];
    h2[t] = 0;
    __syncthreads();
    for (int i = t; i < cb; i += 256) {
        int v = pk[b * CAPB + i];
        ent[i] = v;
        rnk[i] = atomicAdd(&h2[(v >> 20) & 255], 1);   // native ds_add
    }
    __syncthreads();
    int v0 = h2[t];
    sc[t] = v0;
    __syncthreads();
    for (int d = 1; d < 256; d <<= 1) {
        int add = (t >= d) ? sc[t - d] : 0;
        __syncthreads();
        sc[t] += add;
        __syncthreads();
    }
    int excl = sc[t] - v0;
    __syncthreads();
    sc[t] = excl;
    __syncthreads();
    int n = (b << 8) + t;
    if (n < NKEYS) off[n] = base + excl;
    for (int i = t; i < cb; i += 256) {
        int v = ent[i];
        idxx[base + sc[(v >> 20) & 255] + rnk[i]] = v & 0xFFFFF;
    }
}

// ---- conv1 fused: 64 nodes/block, 4 threads/node quadrant slices.
//      5 blocks/CU; sorted idxx feed; no atomics anywhere. ----
__global__ __launch_bounds__(256, 5)
void conv1_fused(const int* __restrict__ idxx, const int* __restrict__ off,
                 const float* __restrict__ x, const int* __restrict__ ei0,
                 const float* __restrict__ ps0, const float* __restrict__ W1,
                 const float* __restrict__ root, const float* __restrict__ bias,
                 float* __restrict__ h1) {
    __shared__ float S4[256 * 25];    // 25.6 KB, thread-private slices
    __shared__ float Sr[64 * 25];     // 6.4 KB reduced
    int t = threadIdx.x;
    int nb = blockIdx.x * 64;
    int q = t & 3, nl = t >> 2;
    int n = nb + nl;
    float* sp = S4 + t * 25;
#pragma unroll
    for (int a = 0; a < 25; a++) sp[a] = 0.f;
    int e0 = off[n], e1 = off[n + 1];
    for (int p = e0 + q; p < e1; p += 4) {
        int e = idxx[p];
        int src = ei0[e];
        int a00, a01, a10, a11; float fx, fy;
        taps4(ps0[2 * e] * (KK - 1), ps0[2 * e + 1] * (KK - 1),
              a00, a01, a10, a11, fx, fy);
        float xv = x[src];
        float gx = 1.f - fx, gy = 1.f - fy;
        sp[a00] += gx * gy * xv; sp[a01] += gx * fy * xv;
        sp[a10] += fx * gy * xv; sp[a11] += fx * fy * xv;
    }
    __syncthreads();
    for (int idx2 = t; idx2 < 64 * 25; idx2 += 256) {
        int n2 = idx2 / 25, a = idx2 - n2 * 25;
        Sr[idx2] = S4[(n2 * 4 + 0) * 25 + a] + S4[(n2 * 4 + 1) * 25 + a] +
                   S4[(n2 * 4 + 2) * 25 + a] + S4[(n2 * 4 + 3) * 25 + a];
    }
    __syncthreads();
    int o = t & 31, ng = t >> 5;
    float w1c[25];
#pragma unroll
    for (int a = 0; a < 25; a++) w1c[a] = W1[a * C1 + o];
    float ro = root[o], bo = bias[o];
    for (int j = 0; j < 8; j++) {
        int nl2 = ng * 8 + j;
        int n2 = nb + nl2;
        float acc = 0.f;
#pragma unroll
        for (int a = 0; a < 25; a++) acc += Sr[nl2 * 25 + a] * w1c[a];
        float invd = 1.f / fmaxf((float)(off[n2 + 1] - off[n2]), 1.f);
        float v = acc * invd + x[n2] * ro + bo;
        h1[n2 * C1 + o] = v > 0.f ? v : expm1f(v);
    }
}

// ---- pool1: [100,28,28,32] -> [100,14,14,32] ----
__global__ void pool1(const float* __restrict__ h1, float* __restrict__ p1) {
    int idx = blockIdx.x * blockDim.x + threadIdx.x;
    if (idx >= N1 * C1) return;
    int o = idx & 31; int t = idx >> 5;
    int c = t % 14; int r = (t / 14) % 14; int b = t / 196;
    const float* base = h1 + (((b * 28 + 2 * r) * 28 + 2 * c) * C1 + o);
    float m = fmaxf(fmaxf(base[0], base[C1]),
                    fmaxf(base[28 * C1], base[28 * C1 + C1]));
    p1[idx] = m;
}

// ---- w2t prep: bf16 transposed W2ext [64 o][832 k]; k<800 -> W2, else root2 ----
__global__ void w2t_prep(const float* __restrict__ W2, const float* __restrict__ root2,
                         unsigned short* __restrict__ w2t) {
    int idx = blockIdx.x * blockDim.x + threadIdx.x;
    if (idx >= 64 * KEXT) return;
    int o = idx / KEXT, k = idx - o * KEXT;
    float v = (k < 800) ? W2[k * 64 + o] : root2[(k - 800) * 64 + o];
    w2t[idx] = f2bf(v);
}

// ---- wt1 prep: fc1w [3136,512] fp32 -> transposed bf16 wt1[512][3136] ----
__global__ void wt1_prep(const float* __restrict__ w, unsigned short* __restrict__ wt1) {
    __shared__ unsigned short tile[64 * 66];
    int t = threadIdx.x;
    int k0 = blockIdx.x * 64, j0 = blockIdx.y * 64;
    int jj = t & 63, ks = t >> 6;
    for (int kk = ks; kk < 64; kk += 4)
        tile[kk * 66 + jj] = f2bf(w[(k0 + kk) * FC1_OUT + j0 + jj]);
    __syncthreads();
    int kk = t & 63, js = t >> 6;
    for (int j2 = js; j2 < 64; j2 += 4)
        wt1[(j0 + j2) * FC1_IN + k0 + kk] = tile[kk * 66 + j2];
}

// ---- conv2 fused (MFMA): 8 nodes/block, ~29 KB LDS -> 5 blocks/CU.
//  Phase0: cooperative staging of src/taps/fracs; Phase1: group-private row
//  RMW (group g owns node g, NO atomics); Phase2: bf16 A-pack applies 1/deg
//  (kc<25); h2 = ELU(U@w2t^T + b2) via MFMA (A rows 8-15 alias 0-7, D rows
//  >=8 discarded). ----
__global__ __launch_bounds__(256, 5)
void conv2_fused(const float* __restrict__ p1, const int* __restrict__ idxx,
                 const int* __restrict__ off, const int* __restrict__ ei1,
                 const float* __restrict__ ps1,
                 const unsigned short* __restrict__ w2t,
                 const float* __restrict__ b2, float* __restrict__ h2) {
    __shared__ float Ul[8 * ULS];           // 26.8 KB
    __shared__ int   es[CH2];
    __shared__ int   et[CH2];
    __shared__ float efx[CH2], efy[CH2];
    int t = threadIdx.x;
    int nb = blockIdx.x * 8;
    int i = t & 31, g = t >> 5;             // channel lane, group = node 0..7
    float* up = Ul + g * ULS;
#pragma unroll
    for (int a = 0; a < 25; a++) up[a * 32 + i] = 0.f;
    up[800 + i] = p1[(nb + g) * C1 + i];
    int e0 = off[N0 + nb], e1 = off[N0 + nb + 8];
    int my0 = off[N0 + nb + g], my1 = off[N0 + nb + g + 1];
    for (int base = e0; base < e1; base += CH2) {
        int nE = min(e1 - base, CH2);
        __syncthreads();
        for (int j = t; j < nE; j += 256) {
            int e = idxx[base + j];
            es[j] = ei1[e];
            int a00, a01, a10, a11; float fx, fy;
            taps4(ps1[2 * e] * (KK - 1), ps1[2 * e + 1] * (KK - 1),
                  a00, a01, a10, a11, fx, fy);
            et[j] = a00 | (a01 << 5) | (a10 << 10) | (a11 << 15);
            efx[j] = fx; efy[j] = fy;
        }
        __syncthreads();
        int r0 = max(my0 - base, 0);
        int r1 = min(my1 - base, nE);
#pragma unroll 2
        for (int j = r0; j < r1; j++) {
            int src = es[j]; int m = et[j];
            float fx = efx[j], fy = efy[j];
            float xv = p1[src * C1 + i];    // coalesced 128B per group
            float gx = 1.f - fx, gy = 1.f - fy;
            up[(m & 31) * 32 + i]         += gx * gy * xv;
            up[((m >> 5) & 31) * 32 + i]  += gx * fy * xv;
            up[((m >> 10) & 31) * 32 + i] += fx * gy * xv;
            up[((m >> 15) & 31) * 32 + i] += fx * fy * xv;
        }
    }
    __syncthreads();
    // phase 2: MFMA. wave wv -> o-tile. D[node=quad*4+r][o=lane&15]
    int wv = t >> 6, lane = t & 63, quad = lane >> 4, lrow = lane & 15;
    f32x4 acc = {0.f, 0.f, 0.f, 0.f};
    int nodeA = lrow & 7;                   // A rows 8-15 alias 0-7
    int dg = off[N0 + nb + nodeA + 1] - off[N0 + nb + nodeA];
    float invd = 1.f / fmaxf((float)dg, 1.f);
    const unsigned short* bbase = w2t + (wv * 16 + lrow) * KEXT;
    const float* abase = Ul + nodeA * ULS;
#pragma unroll
    for (int kc = 0; kc < 26; kc++) {
        float4 a0 = *(const float4*)(abase + kc * 32 + quad * 8);
        float4 a1 = *(const float4*)(abase + kc * 32 + quad * 8 + 4);
        float s = (kc < 25) ? invd : 1.f;
        bf16x8 a;
        a[0] = (short)f2bf(a0.x * s); a[1] = (short)f2bf(a0.y * s);
        a[2] = (short)f2bf(a0.z * s); a[3] = (short)f2bf(a0.w * s);
        a[4] = (short)f2bf(a1.x * s); a[5] = (short)f2bf(a1.y * s);
        a[6] = (short)f2bf(a1.z * s); a[7] = (short)f2bf(a1.w * s);
        bf16x8 b = *(const bf16x8*)(bbase + kc * 32 + quad * 8);
        acc = __builtin_amdgcn_mfma_f32_16x16x32_bf16(a, b, acc, 0, 0, 0);
    }
    if (quad < 2) {                         // nodes 0..7 only
        int o = wv * 16 + lrow;
        float bo = b2[o];
#pragma unroll
        for (int r = 0; r < 4; r++) {
            int node = quad * 4 + r;
            float v = acc[r] + bo;
            v = v > 0.f ? v : expm1f(v);
            h2[(nb + node) * C2 + o] = v;
        }
    }
}

// ---- pool2 -> bf16 [112 x 3136], rows 100..111 zeroed (M-pad for MFMA) ----
__global__ void pool2b(const float* __restrict__ h2, unsigned short* __restrict__ p2b) {
    int idx = blockIdx.x * blockDim.x + threadIdx.x;
    if (idx >= 112 * FC1_IN) return;
    if (idx >= 100 * FC1_IN) { p2b[idx] = 0; return; }
    int o = idx & 63; int t2 = idx >> 6;
    int c = t2 % 14; int r = (t2 / 14) % 14; int b = t2 / 196;
    const float* base = h2 + (((b * 28 + 2 * r) * 28 + 2 * c) * C2 + o);
    float m = fmaxf(fmaxf(base[0], base[C2]),
                    fmaxf(base[28 * C2], base[28 * C2 + C2]));
    p2b[idx] = f2bf(m);
}

// ---- fc1 MFMA: [112,3136]bf16 @ wt1^T -> z1p fp32 partials (2 kz). ----
__global__ void gemm_fc1(const unsigned short* __restrict__ p2b,
                         const unsigned short* __restrict__ wt1,
                         float* __restrict__ z1p) {
    constexpr int AS = 232;              // 224 + 8 pad, 16B aligned
    __shared__ unsigned short as_[16 * AS];   // 7.4 KB
    int t = threadIdx.x;
    int jt = blockIdx.x, mt = blockIdx.y, kz = blockIdx.z;
    int wv = t >> 6, lane = t & 63, quad = lane >> 4, lrow = lane & 15;
    int m0 = mt * 16;
    int kbase = kz * 1568;
    const unsigned short* bbase = wt1 + (jt * 64 + wv * 16 + lrow) * FC1_IN + kbase;
    f32x4 acc = {0.f, 0.f, 0.f, 0.f};
    for (int ch = 0; ch < 7; ch++) {
        __syncthreads();
        for (int slot = t; slot < 448; slot += 256) {   // 16 rows x 28 uint4
            int r = slot / 28, c = slot - (slot / 28) * 28;
            *(uint4*)(as_ + r * AS + c * 8) =
                *(const uint4*)(p2b + (m0 + r) * FC1_IN + kbase + ch * 224 + c * 8);
        }
        __syncthreads();
        const unsigned short* ab = as_ + lrow * AS;
        const unsigned short* bb = bbase + ch * 224;
#pragma unroll
        for (int kk = 0; kk < 7; kk++) {
            bf16x8 a = *(const bf16x8*)(ab + kk * 32 + quad * 8);
            bf16x8 b = *(const bf16x8*)(bb + kk * 32 + quad * 8);
            acc = __builtin_amdgcn_mfma_f32_16x16x32_bf16(a, b, acc, 0, 0, 0);
        }
    }
    int n = jt * 64 + wv * 16 + lrow;
#pragma unroll
    for (int r = 0; r < 4; r++) {
        int m = m0 + quad * 4 + r;
        z1p[kz * (112 * FC1_OUT) + m * FC1_OUT + n] = acc[r];
    }
}

// ---- fc2 + log_softmax fused; sums 2 fc1 partials, applies fc1 bias+ELU ----
__global__ void fc2_lsm(const float* __restrict__ z1p, const float* __restrict__ fc1b,
                        const float* __restrict__ w, const float* __restrict__ fc2b,
                        float* __restrict__ out) {
    int b = blockIdx.x;
    int t = threadIdx.x;
    int wv = t >> 6;
    int lane = t & 63;
    float acc = 0.f;
#pragma unroll
    for (int m = 0; m < 8; m++) {
        int k = lane * 8 + m;
        float xv = fc1b[k] + z1p[b * FC1_OUT + k] + z1p[112 * FC1_OUT + b * FC1_OUT + k];
        xv = xv > 0.f ? xv : expm1f(xv);
        acc += xv * w[k * 10 + wv];
    }
#pragma unroll
    for (int off = 32; off > 0; off >>= 1) acc += __shfl_down(acc, off);
    __shared__ float zs[10];
    if (lane == 0) {
        float z = acc + fc2b[wv];
        zs[wv] = z > 0.f ? z : expm1f(z);
    }
    __syncthreads();
    if (t < 10) {
        float m = -1e30f;
        for (int jj = 0; jj < 10; jj++) m = fmaxf(m, zs[jj]);
        float s = 0.f;
        for (int jj = 0; jj < 10; jj++) s += expf(zs[jj] - m);
        out[b * 10 + t] = zs[t] - m - logf(s);
    }
}

extern "C" void kernel_launch(void* const* d_in, const int* in_sizes, int n_in,
                              void* d_out, int out_size, void* d_ws, size_t ws_size,
                              hipStream_t stream) {
    const float* x     = (const float*)d_in[0];
    const float* ps0   = (const float*)d_in[1];
    const float* ps1   = (const float*)d_in[2];
    const float* W1    = (const float*)d_in[3];
    const float* root1 = (const float*)d_in[4];
    const float* b1    = (const float*)d_in[5];
    const float* W2    = (const float*)d_in[6];
    const float* root2 = (const float*)d_in[7];
    const float* b2v   = (const float*)d_in[8];
    const float* fc1w  = (const float*)d_in[9];
    const float* fc1b  = (const float*)d_in[10];
    const float* fc2w  = (const float*)d_in[11];
    const float* fc2b  = (const float*)d_in[12];
    const int*   ei0   = (const int*)d_in[13];
    const int*   ei1   = (const int*)d_in[14];

    float* ws = (float*)d_ws;
    int* gcur  = (int*)ws;                         //        383  (memset region)
    int* db    = (int*)(ws + 384);                 //        383
    int* off   = (int*)(ws + 768);                 //     98,001
    int* pk    = (int*)(ws + 98772);               //    919,200 (383 x 2400)
    int* idxx  = (int*)(ws + 1017972);             //    784,000
    float* h1  = ws + 1801972;                     //  2,508,800
    float* p1  = ws + 4310772;                     //    627,200
    float* h2  = ws + 4937972;                     //  1,254,400
    unsigned short* p2b = (unsigned short*)(ws + 6192372);  // 175,616 w
    float* z1p = ws + 6367988;                     //    114,688
    unsigned short* w2t = (unsigned short*)(ws + 6482676);  // 26,624 w
    unsigned short* wt1 = (unsigned short*)(ws + 6509300);  // 802,816 w
    // high water: 7,312,116 words = 29.2 MB

    hipMemsetAsync(gcur, 0, (size_t)NCOARSE * sizeof(int), stream);

    coarse_bin<<<(E0 + E1 + 4095) / 4096, 512, 0, stream>>>(ei0, ei1, gcur, pk);
    tiny_scan<<<1, 512, 0, stream>>>(gcur, db, off);
    fine_sort<<<NCOARSE, 256, 0, stream>>>(pk, gcur, db, idxx, off);
    w2t_prep<<<(64 * KEXT + 255) / 256, 256, 0, stream>>>(W2, root2, w2t);
    wt1_prep<<<dim3(49, 8), 256, 0, stream>>>(fc1w, wt1);
    conv1_fused<<<N0 / 64, 256, 0, stream>>>(idxx, off, x, ei0, ps0,
                                             W1, root1, b1, h1);
    pool1<<<(N1 * C1 + 255) / 256, 256, 0, stream>>>(h1, p1);
    conv2_fused<<<N1 / 8, 256, 0, stream>>>(p1, idxx, off, ei1, ps1, w2t, b2v, h2);
    pool2b<<<(112 * FC1_IN + 255) / 256, 256, 0, stream>>>(h2, p2b);
    gemm_fc1<<<dim3(8, 7, 2), 256, 0, stream>>>(p2b, wt1, z1p);
    fc2_lsm<<<BSZ, 640, 0, stream>>>(z1p, fc1b, fc2w, fc2b, (float*)d_out);
}